// Round 3
// baseline (111.585 us; speedup 1.0000x reference)
//
#include <hip/hip_runtime.h>

// PointPillarsScatter: canvas[b, :, y, x] = feat[p, :], last-writer-wins.
// Phase 1: winner[b,y,x] = max(p)+1 via atomicMax (deterministic last writer).
// Phase 2: gather — one thread per (b, y, x/4) cell-quad loops over all 64
// channels: winner read ONCE per 1 KB written, feat rows read as contiguous
// float4s, output written as normal (through-L2) float4 stores — R2's
// nontemporal stores measured ~20% below the rocclr fill kernel's rate on
// the same buffer, so match its store path. unroll 2 keeps only 8 loads in
// flight (lower VGPR -> more waves/CU for gather-latency hiding).

constexpr int HH  = 496;
constexpr int WW  = 432;
constexpr int CC  = 64;
constexpr int HWp = HH * WW;   // 214272
constexpr int W4  = WW / 4;    // 108

typedef float v4f __attribute__((ext_vector_type(4)));

// Zero-initialized device global: the "feature row" of empty cells.
__device__ float g_zero_row[CC];

__global__ void k_winner(const int* __restrict__ coords, int* __restrict__ winner,
                         int wstride, int P) {
    int p = blockIdx.x * blockDim.x + threadIdx.x;
    if (p >= P) return;
    int4 c4 = reinterpret_cast<const int4*>(coords)[p];  // (b, z, y, x)
    atomicMax(&winner[c4.x * wstride + c4.z * WW + c4.w], p + 1);
}

__global__ __launch_bounds__(256) void k_gather_cells(
        const float* __restrict__ feat, const int* __restrict__ winner,
        int wstride, float* __restrict__ out, int total) {
    int t = blockIdx.x * blockDim.x + threadIdx.x;
    if (t >= total) return;
    int x4 = t % W4;  int r = t / W4;
    int y  = r % HH;  int bb = r / HH;

    const int4 win = *reinterpret_cast<const int4*>(
        &winner[bb * wstride + y * WW + x4 * 4]);

    // Empty cells read from the zero row -> unconditional vector loads.
    const float* f0 = (win.x > 0) ? feat + (size_t)(win.x - 1) * CC : g_zero_row;
    const float* f1 = (win.y > 0) ? feat + (size_t)(win.y - 1) * CC : g_zero_row;
    const float* f2 = (win.z > 0) ? feat + (size_t)(win.z - 1) * CC : g_zero_row;
    const float* f3 = (win.w > 0) ? feat + (size_t)(win.w - 1) * CC : g_zero_row;

    float* ob = out + ((size_t)bb * CC * HH + y) * WW + x4 * 4;

    #pragma unroll 2
    for (int cq = 0; cq < CC / 4; ++cq) {
        v4f a = *reinterpret_cast<const v4f*>(f0 + cq * 4);
        v4f b = *reinterpret_cast<const v4f*>(f1 + cq * 4);
        v4f c = *reinterpret_cast<const v4f*>(f2 + cq * 4);
        v4f d = *reinterpret_cast<const v4f*>(f3 + cq * 4);
        float* o = ob + (size_t)cq * 4 * HWp;
        v4f s0 = {a.x, b.x, c.x, d.x};
        v4f s1 = {a.y, b.y, c.y, d.y};
        v4f s2 = {a.z, b.z, c.z, d.z};
        v4f s3 = {a.w, b.w, c.w, d.w};
        *reinterpret_cast<v4f*>(o)           = s0;
        *reinterpret_cast<v4f*>(o + HWp)     = s1;
        *reinterpret_cast<v4f*>(o + 2 * HWp) = s2;
        *reinterpret_cast<v4f*>(o + 3 * HWp) = s3;
    }
}

extern "C" void kernel_launch(void* const* d_in, const int* in_sizes, int n_in,
                              void* d_out, int out_size, void* d_ws, size_t ws_size,
                              hipStream_t stream) {
    const float* feat   = (const float*)d_in[0];
    const int*   coords = (const int*)d_in[1];
    float*       out    = (float*)d_out;

    const int P = in_sizes[0] / CC;        // 96000
    const int B = out_size / (CC * HWp);   // 8

    const size_t winner_bytes = (size_t)B * HWp * sizeof(int);
    const int total = B * HH * W4;         // 428,544 cell-quads

    if (ws_size >= winner_bytes) {
        // --- primary: winner array in workspace ---
        int* winner = (int*)d_ws;
        hipMemsetAsync(winner, 0, winner_bytes, stream);
        k_winner<<<(P + 255) / 256, 256, 0, stream>>>(coords, winner, HWp, P);
        k_gather_cells<<<(total + 255) / 256, 256, 0, stream>>>(
            feat, winner, HWp, out, total);
    } else {
        // --- fallback: winner lives in the c=0 plane of out; each gather
        // thread reads its own quad before overwriting it (no cross-thread
        // overlap), so a single gather pass is still race-free.
        for (int b = 0; b < B; ++b)
            hipMemsetAsync(out + (size_t)b * CC * HWp, 0,
                           (size_t)HWp * sizeof(int), stream);
        k_winner<<<(P + 255) / 256, 256, 0, stream>>>(
            coords, (int*)out, CC * HWp, P);
        k_gather_cells<<<(total + 255) / 256, 256, 0, stream>>>(
            feat, (int*)out, CC * HWp, out, total);
    }
}

// Round 5
// 102.303 us; speedup vs baseline: 1.0907x; 1.0907x over previous
//
#include <hip/hip_runtime.h>

// PointPillarsScatter: canvas[b, :, y, x] = feat[p, :], last-writer-wins.
// Phase 1: memset winner; Phase 2: winner[b,y,x] = max(p)+1 via atomicMax;
// Phase 3: gather — one thread per (b, c-quad, y, x/4): winner int4 read once,
// 4 feat float4 loads, register transpose, 4 nontemporal float4 stores into 4
// consecutive channel planes. Thread order sweeps x,y fastest then c-quad →
// device-wide store stream is near-linear in the output buffer (fill-like
// DRAM row locality), unlike the 64-plane-scattered thread-per-cell version.

constexpr int HH  = 496;
constexpr int WW  = 432;
constexpr int CC  = 64;
constexpr int HWp = HH * WW;   // 214272
constexpr int W4  = WW / 4;    // 108
constexpr int CQ  = CC / 4;    // 16

typedef float v4f __attribute__((ext_vector_type(4)));

// Zero-initialized device global: the "feature row" of empty cells.
__device__ float g_zero_row[CC];

__global__ void k_winner(const int* __restrict__ coords, int* __restrict__ winner,
                         int wstride, int P) {
    int p = blockIdx.x * blockDim.x + threadIdx.x;
    if (p >= P) return;
    int4 c4 = reinterpret_cast<const int4*>(coords)[p];  // (b, z, y, x)
    atomicMax(&winner[c4.x * wstride + c4.z * WW + c4.w], p + 1);
}

__global__ __launch_bounds__(256) void k_gather_cq(
        const float* __restrict__ feat, const int* __restrict__ winner,
        float* __restrict__ out, int total) {
    int t = blockIdx.x * blockDim.x + threadIdx.x;
    if (t >= total) return;
    int x4 = t % W4;  int r = t / W4;
    int y  = r % HH;  r /= HH;
    int cq = r & (CQ - 1);
    int bb = r / CQ;

    const int4 win = *reinterpret_cast<const int4*>(
        &winner[bb * HWp + y * WW + x4 * 4]);

    const int co = cq * 4;
    const float* f0 = (win.x > 0) ? feat + (size_t)(win.x - 1) * CC + co : g_zero_row;
    const float* f1 = (win.y > 0) ? feat + (size_t)(win.y - 1) * CC + co : g_zero_row;
    const float* f2 = (win.z > 0) ? feat + (size_t)(win.z - 1) * CC + co : g_zero_row;
    const float* f3 = (win.w > 0) ? feat + (size_t)(win.w - 1) * CC + co : g_zero_row;

    v4f a = *reinterpret_cast<const v4f*>(f0);
    v4f b = *reinterpret_cast<const v4f*>(f1);
    v4f c = *reinterpret_cast<const v4f*>(f2);
    v4f d = *reinterpret_cast<const v4f*>(f3);

    float* o = out + ((size_t)(bb * CC + co) * HH + y) * WW + x4 * 4;
    v4f s0 = {a.x, b.x, c.x, d.x};
    v4f s1 = {a.y, b.y, c.y, d.y};
    v4f s2 = {a.z, b.z, c.z, d.z};
    v4f s3 = {a.w, b.w, c.w, d.w};
    __builtin_nontemporal_store(s0, reinterpret_cast<v4f*>(o));
    __builtin_nontemporal_store(s1, reinterpret_cast<v4f*>(o + HWp));
    __builtin_nontemporal_store(s2, reinterpret_cast<v4f*>(o + 2 * HWp));
    __builtin_nontemporal_store(s3, reinterpret_cast<v4f*>(o + 3 * HWp));
}

// ---- fallback gather (ws too small): winner lives in out's c=0 plane.
// Thread-per-cell (reads its own winner quad exactly once before overwriting
// it) — the c-quad version would race on plane 0 here.
__global__ __launch_bounds__(256) void k_gather_cells(
        const float* __restrict__ feat, const int* __restrict__ winner,
        int wstride, float* __restrict__ out, int total) {
    int t = blockIdx.x * blockDim.x + threadIdx.x;
    if (t >= total) return;
    int x4 = t % W4;  int r = t / W4;
    int y  = r % HH;  int bb = r / HH;
    const int4 win = *reinterpret_cast<const int4*>(
        &winner[bb * wstride + y * WW + x4 * 4]);
    const float* f0 = (win.x > 0) ? feat + (size_t)(win.x - 1) * CC : g_zero_row;
    const float* f1 = (win.y > 0) ? feat + (size_t)(win.y - 1) * CC : g_zero_row;
    const float* f2 = (win.z > 0) ? feat + (size_t)(win.z - 1) * CC : g_zero_row;
    const float* f3 = (win.w > 0) ? feat + (size_t)(win.w - 1) * CC : g_zero_row;
    float* ob = out + ((size_t)bb * CC * HH + y) * WW + x4 * 4;
    #pragma unroll 4
    for (int cq = 0; cq < CQ; ++cq) {
        v4f a = *reinterpret_cast<const v4f*>(f0 + cq * 4);
        v4f b = *reinterpret_cast<const v4f*>(f1 + cq * 4);
        v4f c = *reinterpret_cast<const v4f*>(f2 + cq * 4);
        v4f d = *reinterpret_cast<const v4f*>(f3 + cq * 4);
        float* o = ob + (size_t)cq * 4 * HWp;
        v4f s0 = {a.x, b.x, c.x, d.x};
        v4f s1 = {a.y, b.y, c.y, d.y};
        v4f s2 = {a.z, b.z, c.z, d.z};
        v4f s3 = {a.w, b.w, c.w, d.w};
        __builtin_nontemporal_store(s0, reinterpret_cast<v4f*>(o));
        __builtin_nontemporal_store(s1, reinterpret_cast<v4f*>(o + HWp));
        __builtin_nontemporal_store(s2, reinterpret_cast<v4f*>(o + 2 * HWp));
        __builtin_nontemporal_store(s3, reinterpret_cast<v4f*>(o + 3 * HWp));
    }
}

extern "C" void kernel_launch(void* const* d_in, const int* in_sizes, int n_in,
                              void* d_out, int out_size, void* d_ws, size_t ws_size,
                              hipStream_t stream) {
    const float* feat   = (const float*)d_in[0];
    const int*   coords = (const int*)d_in[1];
    float*       out    = (float*)d_out;

    const int P = in_sizes[0] / CC;        // 96000
    const int B = out_size / (CC * HWp);   // 8

    const size_t winner_bytes = (size_t)B * HWp * sizeof(int);

    if (ws_size >= winner_bytes) {
        // --- primary: winner array in workspace ---
        int* winner = (int*)d_ws;
        hipMemsetAsync(winner, 0, winner_bytes, stream);
        k_winner<<<(P + 255) / 256, 256, 0, stream>>>(coords, winner, HWp, P);
        const int total = B * CQ * HH * W4;     // 6,856,704
        k_gather_cq<<<(total + 255) / 256, 256, 0, stream>>>(
            feat, winner, out, total);
    } else {
        // --- fallback: winner in out's c=0 plane, thread-per-cell gather ---
        for (int b = 0; b < B; ++b)
            hipMemsetAsync(out + (size_t)b * CC * HWp, 0,
                           (size_t)HWp * sizeof(int), stream);
        k_winner<<<(P + 255) / 256, 256, 0, stream>>>(
            coords, (int*)out, CC * HWp, P);
        const int total = B * HH * W4;
        k_gather_cells<<<(total + 255) / 256, 256, 0, stream>>>(
            feat, (int*)out, CC * HWp, out, total);
    }
}

// Round 6
// 94.853 us; speedup vs baseline: 1.1764x; 1.0785x over previous
//
#include <hip/hip_runtime.h>

// PointPillarsScatter: canvas[b, :, y, x] = feat[p, :], last-writer-wins.
// Phase 1: memset winner; Phase 2: winner[b,y,x] = max(p)+1 via atomicMax;
// Phase 3: LDS-transpose gather. Block owns 32 consecutive quads (128 cells):
//   load:  16 lanes per pillar row -> 256B coalesced feat reads into
//          rows[128][65] (pad 65 kills the power-of-2 bank stride);
//          empty cells write zeros (no global read).
//   store: 32 lanes per channel assemble transposed v4f from LDS and write
//          512B-contiguous nontemporal runs per channel plane.
// This removes the per-lane-divergent feat gather (27.4M scattered 16B
// transactions) that capped the previous gather at ~5.5 TB/s effective.

constexpr int HH  = 496;
constexpr int WW  = 432;
constexpr int CC  = 64;
constexpr int HWp = HH * WW;   // 214272
constexpr int W4  = WW / 4;    // 108
constexpr int QPB   = 32;      // quads per block
constexpr int CELLS = QPB * 4; // 128
constexpr int PAD   = 65;      // LDS row stride in floats

typedef float v4f __attribute__((ext_vector_type(4)));

// Zero-initialized device global: the "feature row" of empty cells (fallback).
__device__ float g_zero_row[CC];

__global__ void k_winner(const int* __restrict__ coords, int* __restrict__ winner,
                         int wstride, int P) {
    int p = blockIdx.x * blockDim.x + threadIdx.x;
    if (p >= P) return;
    int4 c4 = reinterpret_cast<const int4*>(coords)[p];  // (b, z, y, x)
    atomicMax(&winner[c4.x * wstride + c4.z * WW + c4.w], p + 1);
}

__global__ __launch_bounds__(256) void k_gather_lds(
        const float* __restrict__ feat, const int* __restrict__ winner,
        float* __restrict__ out, int blocksPerBatch) {
    __shared__ float rows[CELLS * PAD];   // 33,280 B

    const int bb       = blockIdx.x / blocksPerBatch;
    const int cellbase = (blockIdx.x % blocksPerBatch) * (QPB * 4);
    const int t   = threadIdx.x;
    const int grp = t >> 4;   // 0..15 (row group in load phase)
    const int ln  = t & 15;   // 0..15 (lane within row)

    const int* wbase = winner + bb * HWp + cellbase;

    // --- load phase: 8 rounds x 16 rows, 256B coalesced per row ---
    #pragma unroll
    for (int r = 0; r < 8; ++r) {
        int row = r * 16 + grp;
        int w = wbase[row];                       // broadcast within 16-lane group
        v4f v = {0.0f, 0.0f, 0.0f, 0.0f};
        if (w > 0)
            v = *reinterpret_cast<const v4f*>(feat + (size_t)(w - 1) * CC + ln * 4);
        *reinterpret_cast<v4f*>(&rows[row * PAD + ln * 4]) = v;
    }
    __syncthreads();

    // --- store phase: 8 rounds x 8 channels, 32 lanes per channel ---
    const int qv = t & 31;    // which v4f within the channel's 512B span
    const int cg = t >> 5;    // 0..7
    float* obase = out + (size_t)bb * CC * HWp + cellbase;
    #pragma unroll
    for (int r = 0; r < 8; ++r) {
        int c = r * 8 + cg;
        v4f s;
        s.x = rows[(qv * 4 + 0) * PAD + c];
        s.y = rows[(qv * 4 + 1) * PAD + c];
        s.z = rows[(qv * 4 + 2) * PAD + c];
        s.w = rows[(qv * 4 + 3) * PAD + c];
        __builtin_nontemporal_store(
            s, reinterpret_cast<v4f*>(obase + (size_t)c * HWp + qv * 4));
    }
}

// ---- fallback gather (ws too small): winner lives in out's c=0 plane.
// Thread-per-cell, reads its own winner quad exactly once before overwriting.
__global__ __launch_bounds__(256) void k_gather_cells(
        const float* __restrict__ feat, const int* __restrict__ winner,
        int wstride, float* __restrict__ out, int total) {
    int t = blockIdx.x * blockDim.x + threadIdx.x;
    if (t >= total) return;
    int x4 = t % W4;  int r = t / W4;
    int y  = r % HH;  int bb = r / HH;
    const int4 win = *reinterpret_cast<const int4*>(
        &winner[bb * wstride + y * WW + x4 * 4]);
    const float* f0 = (win.x > 0) ? feat + (size_t)(win.x - 1) * CC : g_zero_row;
    const float* f1 = (win.y > 0) ? feat + (size_t)(win.y - 1) * CC : g_zero_row;
    const float* f2 = (win.z > 0) ? feat + (size_t)(win.z - 1) * CC : g_zero_row;
    const float* f3 = (win.w > 0) ? feat + (size_t)(win.w - 1) * CC : g_zero_row;
    float* ob = out + ((size_t)bb * CC * HH + y) * WW + x4 * 4;
    #pragma unroll 4
    for (int cq = 0; cq < CC / 4; ++cq) {
        v4f a = *reinterpret_cast<const v4f*>(f0 + cq * 4);
        v4f b = *reinterpret_cast<const v4f*>(f1 + cq * 4);
        v4f c = *reinterpret_cast<const v4f*>(f2 + cq * 4);
        v4f d = *reinterpret_cast<const v4f*>(f3 + cq * 4);
        float* o = ob + (size_t)cq * 4 * HWp;
        v4f s0 = {a.x, b.x, c.x, d.x};
        v4f s1 = {a.y, b.y, c.y, d.y};
        v4f s2 = {a.z, b.z, c.z, d.z};
        v4f s3 = {a.w, b.w, c.w, d.w};
        __builtin_nontemporal_store(s0, reinterpret_cast<v4f*>(o));
        __builtin_nontemporal_store(s1, reinterpret_cast<v4f*>(o + HWp));
        __builtin_nontemporal_store(s2, reinterpret_cast<v4f*>(o + 2 * HWp));
        __builtin_nontemporal_store(s3, reinterpret_cast<v4f*>(o + 3 * HWp));
    }
}

extern "C" void kernel_launch(void* const* d_in, const int* in_sizes, int n_in,
                              void* d_out, int out_size, void* d_ws, size_t ws_size,
                              hipStream_t stream) {
    const float* feat   = (const float*)d_in[0];
    const int*   coords = (const int*)d_in[1];
    float*       out    = (float*)d_out;

    const int P = in_sizes[0] / CC;        // 96000
    const int B = out_size / (CC * HWp);   // 8

    const size_t winner_bytes = (size_t)B * HWp * sizeof(int);

    if (ws_size >= winner_bytes) {
        // --- primary: winner array in workspace ---
        int* winner = (int*)d_ws;
        hipMemsetAsync(winner, 0, winner_bytes, stream);
        k_winner<<<(P + 255) / 256, 256, 0, stream>>>(coords, winner, HWp, P);
        const int blocksPerBatch = (HH * W4) / QPB;   // 53568/32 = 1674
        const int nblocks = B * blocksPerBatch;       // 13392
        k_gather_lds<<<nblocks, 256, 0, stream>>>(feat, winner, out, blocksPerBatch);
    } else {
        // --- fallback: winner in out's c=0 plane, thread-per-cell gather ---
        for (int b = 0; b < B; ++b)
            hipMemsetAsync(out + (size_t)b * CC * HWp, 0,
                           (size_t)HWp * sizeof(int), stream);
        k_winner<<<(P + 255) / 256, 256, 0, stream>>>(
            coords, (int*)out, CC * HWp, P);
        const int total = B * HH * W4;
        k_gather_cells<<<(total + 255) / 256, 256, 0, stream>>>(
            feat, (int*)out, CC * HWp, out, total);
    }
}